// Round 6
// baseline (55.325 us; speedup 1.0000x reference)
//
#include <hip/hip_runtime.h>
#include <math.h>

// NEAT forward, round 6.
//  - prep rewritten as wave-parallel ballot counting-sort: lane = edge,
//    16-iter __ballot/__popcll loop computes (class start, rank) with no
//    LDS histogram (R5 prep was 132 lone waves x 64 serial LDS RMW chains
//    ~200cyc each = 12 us). Schedule emitted is IDENTICAL to R5:
//    slot = (start[c] + rank - sigma(l)) & 63, sigma(l) = 4*(l&15)+(l>>4).
//  - fwd kernel unchanged from R5 (43 us, 9.3e6 conflict cycles).

#define N_IN    512
#define NLAYER  9
#define DEG     64
#define BATCH   1024
#define BPB     4
#define THREADS 1024
#define TOTAL_N 8960            // 512 + 8*1024 + 256
#define N_OUT   256
#define NGROUP  132             // 8448 edge-owning neurons / 64

union H4 { uint2 u; _Float16 h[4]; };
union H2 { unsigned u; _Float16 h[2]; };
union HS { _Float16 h; unsigned short s; };

// ---- prep: ballot counting-sort + class-strided rotation ----
// block = 256 threads (4 waves), each wave handles 16 neurons of group g.
__global__ __launch_bounds__(256)
void neat_prep(const float* __restrict__ wts,
               const int*   __restrict__ sidx,
               uint4*       __restrict__ rec)
{
    // padded: neuron stride 17 quads so copy-out LDS reads spread banks
    __shared__ unsigned short srec[64 * 17 * 8];   // 17,408 B

    const int tid  = threadIdx.x;
    const int g    = blockIdx.x;
    const int wave = tid >> 6;
    const int lane = tid & 63;
    const unsigned long long lt = (1ull << lane) - 1ull;

    #pragma unroll 2
    for (int k = 0; k < 16; ++k) {
        const int l = (wave << 4) + k;             // neuron within group, 0..63
        const int j = (g << 12) + (l << 6) + lane; // this lane's edge (coalesced)
        const int idx = sidx[j];
        HS w; w.h = (_Float16)wts[j];

        const int c = idx & 15;                    // bank-pair class
        int start = 0, rank = 0;
        #pragma unroll
        for (int cc = 0; cc < 16; ++cc) {
            const unsigned long long m = __ballot(c == cc);
            if (cc < c)       start += (int)__popcll(m);
            else if (cc == c) rank   = (int)__popcll(m & lt);
        }

        const int sigma = ((l & 15) << 2) | (l >> 4);
        const int slot  = ((start + rank) - sigma) & 63;
        const int q = slot >> 2, gg = slot & 3;
        srec[((l * 17 + q) << 3) + gg]     = (unsigned short)idx;
        srec[((l * 17 + q) << 3) + 4 + gg] = w.s;
    }
    __syncthreads();

    // copy out: rec[g*1024 + q*64 + l] = srec quad (l, q)
    const uint4* sr = reinterpret_cast<const uint4*>(srec);
    for (int r = tid; r < 1024; r += 256) {
        const int q = r >> 6, l = r & 63;
        rec[(g << 10) + r] = sr[l * 17 + q];
    }
}

__global__ __launch_bounds__(THREADS, 4)
void neat_fwd(const float* __restrict__ in,
              const uint4* __restrict__ rec,
              float*       __restrict__ out)
{
    __shared__ _Float16 act[TOTAL_N * BPB];        // [neuron][batch], 71,680 B

    const int tid   = threadIdx.x;
    const int bbase = blockIdx.x * BPB;

    // ---- stage inputs (f32 -> f16) ----
    {
        const float* src = in + bbase * N_IN;
        for (int t = tid; t < BPB * N_IN; t += THREADS) {
            int j = t >> 9;           // batch sub
            int i = t & (N_IN - 1);   // input neuron
            act[i * BPB + j] = (_Float16)src[t];
        }
    }
    __syncthreads();

    int recBase = 0;
    int nb      = N_IN;
    #pragma unroll 1
    for (int layer = 0; layer < NLAYER; ++layer) {
        const int n = (layer < NLAYER - 1) ? 1024 : N_OUT;
        if (tid < n) {
            const int neuron = tid;
            const uint4* rp = rec + recBase + ((neuron >> 6) << 10) + (neuron & 63);

            // prefetch all 16 records (static-indexed)
            uint4 r[16];
            #pragma unroll
            for (int q = 0; q < 16; ++q) r[q] = rp[q << 6];

            float4 acc = make_float4(0.f, 0.f, 0.f, 0.f);
            #pragma unroll
            for (int q = 0; q < 16; ++q) {
                const uint4 r4 = r[q];
                H4 g0, g1, g2, g3;
                g0.u = *reinterpret_cast<const uint2*>(act + ((r4.x & 0xffffu) << 2));
                g1.u = *reinterpret_cast<const uint2*>(act + ((r4.x >> 16) << 2));
                g2.u = *reinterpret_cast<const uint2*>(act + ((r4.y & 0xffffu) << 2));
                g3.u = *reinterpret_cast<const uint2*>(act + ((r4.y >> 16) << 2));
                H2 wz, ww; wz.u = r4.z; ww.u = r4.w;
                acc.x += (float)g0.h[0] * (float)wz.h[0];
                acc.y += (float)g0.h[1] * (float)wz.h[0];
                acc.z += (float)g0.h[2] * (float)wz.h[0];
                acc.w += (float)g0.h[3] * (float)wz.h[0];
                acc.x += (float)g1.h[0] * (float)wz.h[1];
                acc.y += (float)g1.h[1] * (float)wz.h[1];
                acc.z += (float)g1.h[2] * (float)wz.h[1];
                acc.w += (float)g1.h[3] * (float)wz.h[1];
                acc.x += (float)g2.h[0] * (float)ww.h[0];
                acc.y += (float)g2.h[1] * (float)ww.h[0];
                acc.z += (float)g2.h[2] * (float)ww.h[0];
                acc.w += (float)g2.h[3] * (float)ww.h[0];
                acc.x += (float)g3.h[0] * (float)ww.h[1];
                acc.y += (float)g3.h[1] * (float)ww.h[1];
                acc.z += (float)g3.h[2] * (float)ww.h[1];
                acc.w += (float)g3.h[3] * (float)ww.h[1];
            }

            float4 sg;
            sg.x = 1.f / (1.f + __expf(-acc.x));
            sg.y = 1.f / (1.f + __expf(-acc.y));
            sg.z = 1.f / (1.f + __expf(-acc.z));
            sg.w = 1.f / (1.f + __expf(-acc.w));

            if (layer < NLAYER - 1) {
                H4 p;
                p.h[0] = (_Float16)sg.x; p.h[1] = (_Float16)sg.y;
                p.h[2] = (_Float16)sg.z; p.h[3] = (_Float16)sg.w;
                *reinterpret_cast<uint2*>(act + ((nb + neuron) << 2)) = p.u;
            } else {
                float* op = out + neuron;           // f32 output, never quantized
                op[(bbase + 0) * N_OUT] = sg.x;
                op[(bbase + 1) * N_OUT] = sg.y;
                op[(bbase + 2) * N_OUT] = sg.z;
                op[(bbase + 3) * N_OUT] = sg.w;
            }
        }
        __syncthreads();
        recBase += n << 4;   // n * DEG / 4 records
        nb      += n;
    }
}

extern "C" void kernel_launch(void* const* d_in, const int* in_sizes, int n_in,
                              void* d_out, int out_size, void* d_ws, size_t ws_size,
                              hipStream_t stream)
{
    const float* in  = (const float*)d_in[0];
    const float* wts = (const float*)d_in[1];
    const int*   sx  = (const int*)d_in[2];
    float*       out = (float*)d_out;
    uint4*       rec = (uint4*)d_ws;    // 135,168 * 16 = 2,162,688 B

    neat_prep<<<NGROUP, 256, 0, stream>>>(wts, sx, rec);
    neat_fwd<<<BATCH / BPB, THREADS, 0, stream>>>(in, rec, out);
}